// Round 16
// baseline (256.561 us; speedup 1.0000x reference)
//
#include <hip/hip_runtime.h>
#include <cstdint>
#include <cstddef>

// Problem constants (fixed by the reference: B=8192, F=1024, N=4096)
#define B_DIM 8192
#define F_DIM 1024
#define N_DIM 4096

// R18 (resubmit after broker timeout): dispatch-count reduction. R17
// post-mortem: fast path works (332->214, absmax 0) but kernel work is only
// ~45us -- the rest is ~60-80us fixed harness overhead + ~15-25us PER
// DISPATCH. So: 6 dispatches -> 3.
//  1) k_prep = rownorms + fp8-quantize + rowsum-zero fused (one 80MB read).
//  2) k_guard eliminated: per-row bound relaxed to a SCALAR bound
//     (maxX,maxY,maxW,maxB via per-block-reduced atomicMax; int-bit max is
//     order-preserving for non-negative floats). Consumers evaluate the
//     2-comparison certificate inline:
//       L := lnB_floor - maxX*maxY >= 3+1/16   (lse_i >= L, hs=identity)
//       L - maxY*maxW - maxB >= 1+1/16         (out_pre >= 1 -> clamp = 1)
//     Strictly conservative vs R17's per-row check (Cauchy-Schwarz chain);
//     measured-scale margins ~2.3 on both conditions. Stale/garbage maxes
//     can only be too LARGE -> certificate fails -> correct fallback.
//  3) two k_g1 column-half dispatches merged into one (split was only for
//     profiler visibility).
// flag semantics: certified -> k_g1 early-exits, k_g2 fills out with 1.0f.
// not certified -> the harness-verified fp8 MX pipeline runs (128x128 tile,
// 4 waves, 3 blocks/CU -- R13-R16: local optimum; staging BW ~2.9 TB/s per
// co-resident block).
#define BM 128
#define BN 128
#define BK 128

typedef float floatx4 __attribute__((ext_vector_type(4)));
typedef int intx4 __attribute__((ext_vector_type(4)));
typedef int intx8 __attribute__((ext_vector_type(8)));

typedef const __attribute__((address_space(1))) unsigned int* as1_u32cp;
typedef __attribute__((address_space(3))) unsigned int* as3_u32p;

// Async global->LDS 16B copy. LDS dest is wave-uniform base + lane*16.
__device__ __forceinline__ void gload_lds16(const uint8_t* g, uint8_t* l) {
    __builtin_amdgcn_global_load_lds((as1_u32cp)(const unsigned int*)g,
                                     (as3_u32p)(unsigned int*)l, 16, 0, 0);
}

__device__ __forceinline__ float hardswish_f(float l) {
    float g = fminf(fmaxf(l + 3.0f, 0.0f), 6.0f);
    return l * g * (1.0f / 6.0f);
}

// Inline certificate from the 4 atomicMax'ed scalars (see header comment).
// lnB_floor = 9.0109130 < ln(8192); margin 1/16 covers fp32 summation error
// (~1e-4 relative) with ~100x headroom.
__device__ __forceinline__ bool certified(const unsigned int* mx) {
    if (!mx) return false;
    const float maxX = __int_as_float((int)mx[0]);
    const float maxY = __int_as_float((int)mx[1]);
    const float maxW = __int_as_float((int)mx[2]);
    const float maxB = __int_as_float((int)mx[3]);
    const float L = 9.0109130f - maxX * maxY;
    return (L >= 3.0625f) && (L - maxY * maxW - maxB >= 1.0625f);
}

// ---- fused prep: row norms + fp8 e4m3 quantize + rowsum zero -------------
// Blocks 0..5119: 4 waves, one row each. Global row r in 0..20479 maps to
// x (r<8192), y (r<16384), w (else); fp8 dst is contiguous xq|yq|wq, so
// drow = dst + r*1024 for ALL three tensors. Block category is uniform
// (boundaries 2048/4096 fall on block edges). Per-wave: 4 coalesced float4
// loads/lane -> sumsq + cvt_pk_fp8 (coalesced int stores); butterfly reduce;
// block-reduce 4 norms in LDS; ONE atomicMax per block per category
// (~5K atomics total to 4 addresses). w-waves also fold |bias[row]| max.
// Blocks 5120..5127: zero rowsum (8 x 256 float4 = 8192 floats).
__global__ __launch_bounds__(256) void k_prep(
    const float* __restrict__ x, const float* __restrict__ y,
    const float* __restrict__ wt, const float* __restrict__ bias,
    uint8_t* __restrict__ dst, float* __restrict__ rowsum,
    unsigned int* __restrict__ mx) {
    const int b = blockIdx.x;
    if (b >= 5120) {
        const int i = (b - 5120) * 256 + threadIdx.x;   // 0..2047 float4s
        ((float4*)rowsum)[i] = make_float4(0.f, 0.f, 0.f, 0.f);
        return;
    }
    const int t = threadIdx.x;
    const int lane = t & 63;
    const int wv = t >> 6;
    const int row = b * 4 + wv;                          // 0..20479
    const float* src;
    int cat;
    if (row < B_DIM) { src = x + (size_t)row * F_DIM; cat = 0; }
    else if (row < 2 * B_DIM) { src = y + (size_t)(row - B_DIM) * F_DIM; cat = 1; }
    else { src = wt + (size_t)(row - 2 * B_DIM) * F_DIM; cat = 2; }
    uint8_t* drow = dst + (size_t)row * F_DIM;           // contiguous xq|yq|wq

    float s = 0.f;
#pragma unroll
    for (int j = 0; j < 4; ++j) {
        float4 v = ((const float4*)src)[j * 64 + lane];
        s += v.x * v.x + v.y * v.y + v.z * v.z + v.w * v.w;
        int p = __builtin_amdgcn_cvt_pk_fp8_f32(v.x, v.y, 0, false);
        p = __builtin_amdgcn_cvt_pk_fp8_f32(v.z, v.w, p, true);
        ((int*)drow)[j * 64 + lane] = p;
    }
#pragma unroll
    for (int o = 1; o < 64; o <<= 1) s += __shfl_xor(s, o, 64);

    __shared__ float nrm[4];
    __shared__ float bb[4];
    if (lane == 0) {
        nrm[wv] = sqrtf(s);
        bb[wv] = (cat == 2) ? fabsf(bias[row - 2 * B_DIM]) : 0.f;
    }
    __syncthreads();
    if (t == 0 && mx) {
        float m = fmaxf(fmaxf(nrm[0], nrm[1]), fmaxf(nrm[2], nrm[3]));
        atomicMax((int*)&mx[cat], __float_as_int(m));    // non-neg: int order ok
        float mb = fmaxf(fmaxf(bb[0], bb[1]), fmaxf(bb[2], bb[3]));
        if (mb > 0.f) atomicMax((int*)&mx[3], __float_as_int(mb));
    }
}

// ---- fallback GEMM (harness-verified 332us structure, unchanged) ----------
// C = A * B^T, A[M][K], Bm[N][K] row-major fp8 e4m3, fp32 accumulate via
// mfma_scale_f32_16x16x128_f8f6f4 with unit scales (E8M0 0x7F = 2^0).
// LDS XOR-swizzled in 16B chunks: slot (row,c) holds global chunk c^(row&7).
// A-fragment (16x16x128): row=lane&15, k = quad*32 + reg*4 + byte
// -> 32 contiguous bytes = swizzled chunks {(2q)^e, (2q+1)^e}, e=row&7.
// C/D layout: col=lane&15, row=quad*4+reg.
// MODE 1: epilogue sums exp(C[i][j]) into rowsum[i] (scores never hit HBM).
// MODE 2: prologue addv[128]=hardswish(log(rowsum)); epilogue transposed
//         through LDS (stride 132 floats) for coalesced float4 stores of
//         out = clamp(C + bias + addv, -1, 1).
template <int MODE>
__device__ __forceinline__ void gemm_body(
    const uint8_t* __restrict__ A,
    const uint8_t* __restrict__ Bm,
    int K, int N,
    float* __restrict__ rowsum,
    const float* __restrict__ bias,
    float* __restrict__ out) {
    // 33.8 KB: staging (32 KB) during K-loop; 64x132 float pad-buffer after.
    __shared__ __align__(16) uint8_t smem[64 * 132 * 4];
    __shared__ float addv[BM];     // separate: must not alias epi
    uint8_t* As = smem;            // 16 KB
    uint8_t* Bs = smem + 16384;    // 16 KB
    float* epi = (float*)smem;     // MODE 2 epilogue reuse

    const int t = threadIdx.x;
    const int w = t >> 6;
    const int lane = t & 63;
    const int quad = lane >> 4;
    const int lc = lane & 15;
    const int wm = w >> 1;   // wave row (0..1), 64 rows each
    const int wn = w & 1;    // wave col (0..1), 64 cols each
    const int rowBase = blockIdx.y * BM;
    const int colBase = blockIdx.x * BN;

    if constexpr (MODE == 2) {
        // one log per thread; published by the K-loop's first __syncthreads()
        if (t < BM) addv[t] = hardswish_f(logf(rowsum[rowBase + t]));
    }

    floatx4 acc[4][4];
#pragma unroll
    for (int mi = 0; mi < 4; ++mi)
#pragma unroll
        for (int ni = 0; ni < 4; ++ni)
            acc[mi][ni] = (floatx4){0.f, 0.f, 0.f, 0.f};

    const int nIter = K / BK;
    for (int kt = 0; kt < nIter; ++kt) {
        __syncthreads();  // prior iteration's LDS reads complete (+ addv publish)
#pragma unroll
        for (int c = 0; c < 4; ++c) {
            const int idx = c * 256 + t;       // 0..1023 -> 1024 16B chunks each
            const int row = idx >> 3;          // 0..127
            const int cg = (idx & 7) ^ (row & 7);
            gload_lds16(A + (size_t)(rowBase + row) * K + kt * BK + cg * 16, As + idx * 16);
            gload_lds16(Bm + (size_t)(colBase + row) * K + kt * BK + cg * 16, Bs + idx * 16);
        }
        __syncthreads();  // drains vmcnt: staged data visible

        intx8 af[4], bf[4];
#pragma unroll
        for (int mi = 0; mi < 4; ++mi) {
            const int row = wm * 64 + mi * 16 + lc;
            const int e = row & 7;
            ((intx4*)&af[mi])[0] = *(const intx4*)(As + row * BK + ((2 * quad) ^ e) * 16);
            ((intx4*)&af[mi])[1] = *(const intx4*)(As + row * BK + ((2 * quad + 1) ^ e) * 16);
        }
#pragma unroll
        for (int ni = 0; ni < 4; ++ni) {
            const int row = wn * 64 + ni * 16 + lc;
            const int e = row & 7;
            ((intx4*)&bf[ni])[0] = *(const intx4*)(Bs + row * BK + ((2 * quad) ^ e) * 16);
            ((intx4*)&bf[ni])[1] = *(const intx4*)(Bs + row * BK + ((2 * quad + 1) ^ e) * 16);
        }
#pragma unroll
        for (int mi = 0; mi < 4; ++mi)
#pragma unroll
            for (int ni = 0; ni < 4; ++ni)
                acc[mi][ni] = __builtin_amdgcn_mfma_scale_f32_16x16x128_f8f6f4(
                    af[mi], bf[ni], acc[mi][ni],
                    0, 0,                      // cbsz=fp8(e4m3), blgp=fp8(e4m3)
                    0, 0x7F7F7F7F,             // A scale: 1.0
                    0, 0x7F7F7F7F);            // B scale: 1.0
    }

    if constexpr (MODE == 1) {
        // sum exp over this wave's 64 columns for each of its 64 rows
#pragma unroll
        for (int mi = 0; mi < 4; ++mi) {
#pragma unroll
            for (int r = 0; r < 4; ++r) {
                float p = 0.f;
#pragma unroll
                for (int ni = 0; ni < 4; ++ni) p += __expf(acc[mi][ni][r]);
                // butterfly over the 16 columns held by this quad's 16 lanes
                p += __shfl_xor(p, 1, 16);
                p += __shfl_xor(p, 2, 16);
                p += __shfl_xor(p, 4, 16);
                p += __shfl_xor(p, 8, 16);
                if (lc == 0) {
                    int row = rowBase + wm * 64 + mi * 16 + quad * 4 + r;
                    atomicAdd(&rowsum[row], p);
                }
            }
        }
    } else {
        // Two halves (64 rows each): wave-row h dumps its (bias+addv+clamp)ed
        // tile into epi[64][132], then all 256 threads store coalesced float4.
#pragma unroll
        for (int h = 0; h < 2; ++h) {
            __syncthreads();  // epi free (staging reads / prior half done)
            if (wm == h) {
#pragma unroll
                for (int mi = 0; mi < 4; ++mi) {
                    const int lr0 = mi * 16 + quad * 4;    // local row 0..60
#pragma unroll
                    for (int ni = 0; ni < 4; ++ni) {
                        const int c = wn * 64 + ni * 16 + lc;
                        const float bv = bias[colBase + c];
#pragma unroll
                        for (int r = 0; r < 4; ++r) {
                            float v = acc[mi][ni][r] + bv + addv[h * 64 + lr0 + r];
                            v = fminf(fmaxf(v, -1.0f), 1.0f);
                            epi[(lr0 + r) * 132 + c] = v;
                        }
                    }
                }
            }
            __syncthreads();  // epi visible to all
#pragma unroll
            for (int k = 0; k < 8; ++k) {
                const int idx = k * 256 + t;     // 0..2047
                const int row = idx >> 5;        // 0..63
                const int c4 = (idx & 31) * 4;   // 0..124
                float4 v = *(const float4*)&epi[row * 132 + c4];
                *(float4*)&out[(size_t)(rowBase + h * 64 + row) * N + colBase + c4] = v;
            }
        }
    }
}

__global__ __launch_bounds__(256, 3) void k_g1(
    const uint8_t* __restrict__ A, const uint8_t* __restrict__ Bm,
    int K, int N, float* __restrict__ rowsum, const unsigned int* mx) {
    if (certified(mx)) return;
    gemm_body<1>(A, Bm, K, N, rowsum, nullptr, nullptr);
}

__global__ __launch_bounds__(256, 3) void k_g2(
    const uint8_t* __restrict__ A, const uint8_t* __restrict__ Bm,
    int K, int N, float* __restrict__ rowsum,
    const float* __restrict__ bias, float* __restrict__ out,
    const unsigned int* mx) {
    if (certified(mx)) {
        // Certified saturation: out tile = 1.0f (coalesced float4 stores).
        const int rowBase = blockIdx.y * BM;
        const int colBase = blockIdx.x * BN;
        const int t = threadIdx.x;
        const float4 one = make_float4(1.f, 1.f, 1.f, 1.f);
#pragma unroll
        for (int k = 0; k < 16; ++k) {
            const int idx = k * 256 + t;     // 0..4095
            const int row = idx >> 5;        // 0..127
            const int c4 = (idx & 31) * 4;   // 0..124
            *(float4*)&out[(size_t)(rowBase + row) * N + colBase + c4] = one;
        }
        return;
    }
    gemm_body<2>(A, Bm, K, N, rowsum, bias, out);
}

extern "C" void kernel_launch(void* const* d_in, const int* in_sizes, int n_in,
                              void* d_out, int out_size, void* d_ws, size_t ws_size,
                              hipStream_t stream) {
    const float* x = (const float*)d_in[0];     // [B, F]
    const float* y = (const float*)d_in[1];     // [B, F]
    const float* wt = (const float*)d_in[2];    // [N, F]
    const float* bias = (const float*)d_in[3];  // [N]
    float* out = (float*)d_out;                 // [B, N]

    // Workspace: xq 8MB | yq 8MB | wq 4MB | rowsum 32KB | mx[4] (16B)
    uint8_t* xq = (uint8_t*)d_ws;
    uint8_t* yq = xq + (size_t)B_DIM * F_DIM;
    uint8_t* wq = yq + (size_t)B_DIM * F_DIM;
    float* rowsum = (float*)(wq + (size_t)N_DIM * F_DIM);
    unsigned int* mx = (unsigned int*)(rowsum + B_DIM);
    const size_t NEED = (size_t)(2 * B_DIM * F_DIM + N_DIM * F_DIM)
                        + (size_t)B_DIM * 4 + 16;

    unsigned int* mxp = nullptr;
    if (ws_size >= NEED) {
        // Zero the 4 max slots (capture-safe memset node). Even if stale,
        // atomicMax can only make them larger -> certificate fails -> safe.
        hipMemsetAsync(mx, 0, 16, stream);
        mxp = mx;
    }

    // 1) fused norms + quantize + rowsum-zero (+ atomicMax scalars)
    k_prep<<<5 * B_DIM / 8 + 8, 256, 0, stream>>>(x, y, wt, bias, xq, rowsum, mxp);

    // 2) scores = x . y^T, fused exp-rowsum (single merged dispatch;
    //    early-exits when certificate holds)
    k_g1<<<dim3(B_DIM / BN, B_DIM / BM), 256, 0, stream>>>(
        xq, yq, F_DIM, B_DIM, rowsum, mxp);

    // 3) out = y . w^T + bias + hardswish(log(rowsum)), clamped
    //    (or certified fill of 1.0f)
    k_g2<<<dim3(N_DIM / BN, B_DIM / BM), 256, 0, stream>>>(
        yq, wq, F_DIM, N_DIM, rowsum, bias, out, mxp);
}

// Round 20
// 216.616 us; speedup vs baseline: 1.1844x; 1.1844x over previous
//
#include <hip/hip_runtime.h>
#include <cstdint>
#include <cstddef>

// Problem constants (fixed by the reference: B=8192, F=1024, N=4096)
#define B_DIM 8192
#define F_DIM 1024
#define N_DIM 4096

// R19 (resubmit x3 after broker timeouts): fix R18's k_prep atomic
// serialization (measured 84us, 5x roofline; ~10K same-cache-line atomicMax
// at ~8ns each = the entire stall).
//  - atomics hashed over 64 slots/category (mxs[4][64], 1KB): ~8 atomics
//    per slot across ~16 lines -> parallel, ~1-2us tail.
//  - 16 rows/block (4/wave sequential): 1288 blocks, 1536 atomics, 4x MLP.
//  - consumers reduce the 64 slots with a lane-strided load + 6-shfl
//    butterfly (wave-uniform; L2-hit) -> certificate stays inline.
// Semantics unchanged from R18: scalar Cauchy-Schwarz certificate
//   L := lnB_floor - maxX*maxY >= 3+1/16  (lse_i >= L, hardswish=identity)
//   L - maxY*maxW - maxB >= 1+1/16        (out_pre >= 1 -> clamp = 1)
// certified -> k_g1 early-exits, k_g2 fills 1.0f; else the harness-verified
// fp8 MX pipeline runs (128x128 tile, 4 waves, 3 blocks/CU; R13-R16 local
// optimum). Empty slots stay 0 (never lower the max); garbage can only
// over-state -> certificate fails -> safe fallback.
#define BM 128
#define BN 128
#define BK 128

typedef float floatx4 __attribute__((ext_vector_type(4)));
typedef int intx4 __attribute__((ext_vector_type(4)));
typedef int intx8 __attribute__((ext_vector_type(8)));

typedef const __attribute__((address_space(1))) unsigned int* as1_u32cp;
typedef __attribute__((address_space(3))) unsigned int* as3_u32p;

// Async global->LDS 16B copy. LDS dest is wave-uniform base + lane*16.
__device__ __forceinline__ void gload_lds16(const uint8_t* g, uint8_t* l) {
    __builtin_amdgcn_global_load_lds((as1_u32cp)(const unsigned int*)g,
                                     (as3_u32p)(unsigned int*)l, 16, 0, 0);
}

__device__ __forceinline__ float hardswish_f(float l) {
    float g = fminf(fmaxf(l + 3.0f, 0.0f), 6.0f);
    return l * g * (1.0f / 6.0f);
}

// Inline certificate: butterfly-max the 64 hashed slots per category.
// All lanes produce the identical value -> wave-uniform branch; all waves
// read the same stable memory -> block-uniform. lnB_floor = 9.0109130 <
// ln(8192); margin 1/16 covers fp32 summation error with ~100x headroom.
__device__ __forceinline__ bool certified(const unsigned int* mxs) {
    if (!mxs) return false;
    const int lane = threadIdx.x & 63;
    float vX = __int_as_float((int)mxs[0 * 64 + lane]);
    float vY = __int_as_float((int)mxs[1 * 64 + lane]);
    float vW = __int_as_float((int)mxs[2 * 64 + lane]);
    float vB = __int_as_float((int)mxs[3 * 64 + lane]);
#pragma unroll
    for (int o = 1; o < 64; o <<= 1) {
        vX = fmaxf(vX, __shfl_xor(vX, o, 64));
        vY = fmaxf(vY, __shfl_xor(vY, o, 64));
        vW = fmaxf(vW, __shfl_xor(vW, o, 64));
        vB = fmaxf(vB, __shfl_xor(vB, o, 64));
    }
    const float L = 9.0109130f - vX * vY;
    return (L >= 3.0625f) && (L - vY * vW - vB >= 1.0625f);
}

// ---- fused prep: row norms + fp8 e4m3 quantize + rowsum zero -------------
// Blocks 0..1279: 16 rows each (wave wv: rows b*16+wv*4 .. +3, sequential).
// Category uniform per block (b<512 x, <1024 y, else w; boundaries on block
// edges). fp8 dst contiguous xq|yq|wq => drow = dst + row*1024 for all.
// Per row: 4 coalesced float4 loads/lane -> sumsq + cvt_pk_fp8 (coalesced
// int stores); butterfly; wave keeps max sumsq (sqrt once). Block-reduce 4
// wave maxima in LDS; ONE hashed atomicMax per block per category
// (+1 for bias on w-blocks): 1536 atomics over 256 slots in ~16 lines.
// Blocks 1280..1287: zero rowsum (8 x 256 float4 = 8192 floats).
__global__ __launch_bounds__(256) void k_prep(
    const float* __restrict__ x, const float* __restrict__ y,
    const float* __restrict__ wt, const float* __restrict__ bias,
    uint8_t* __restrict__ dst, float* __restrict__ rowsum,
    unsigned int* __restrict__ mxs) {
    const int b = blockIdx.x;
    if (b >= 1280) {
        const int i = (b - 1280) * 256 + threadIdx.x;   // 0..2047 float4s
        ((float4*)rowsum)[i] = make_float4(0.f, 0.f, 0.f, 0.f);
        return;
    }
    const int t = threadIdx.x;
    const int lane = t & 63;
    const int wv = t >> 6;
    const int cat = (b < 512) ? 0 : (b < 1024 ? 1 : 2);
    const float* base = (cat == 0) ? x : (cat == 1 ? y : wt);
    const int catRow0 = cat * B_DIM;                     // 0 | 8192 | 16384

    float wmaxs = 0.f;   // max sumsq over this wave's 4 rows (all lanes)
    float wmaxb = 0.f;   // max |bias| (lane 0 only, cat 2 only)
#pragma unroll
    for (int r = 0; r < 4; ++r) {
        const int row = b * 16 + wv * 4 + r;             // global 0..20479
        const float* src = base + (size_t)(row - catRow0) * F_DIM;
        uint8_t* drow = dst + (size_t)row * F_DIM;       // contiguous xq|yq|wq
        float s = 0.f;
#pragma unroll
        for (int j = 0; j < 4; ++j) {
            float4 v = ((const float4*)src)[j * 64 + lane];
            s += v.x * v.x + v.y * v.y + v.z * v.z + v.w * v.w;
            int p = __builtin_amdgcn_cvt_pk_fp8_f32(v.x, v.y, 0, false);
            p = __builtin_amdgcn_cvt_pk_fp8_f32(v.z, v.w, p, true);
            ((int*)drow)[j * 64 + lane] = p;
        }
#pragma unroll
        for (int o = 1; o < 64; o <<= 1) s += __shfl_xor(s, o, 64);
        wmaxs = fmaxf(wmaxs, s);
        if (cat == 2 && lane == 0)
            wmaxb = fmaxf(wmaxb, fabsf(bias[row - 2 * B_DIM]));
    }

    __shared__ float nrm[4];
    __shared__ float bb[4];
    if (lane == 0) { nrm[wv] = sqrtf(wmaxs); bb[wv] = wmaxb; }
    __syncthreads();
    if (t == 0 && mxs) {
        float m = fmaxf(fmaxf(nrm[0], nrm[1]), fmaxf(nrm[2], nrm[3]));
        atomicMax((int*)&mxs[cat * 64 + (b & 63)], __float_as_int(m));
        if (cat == 2) {
            float mb = fmaxf(fmaxf(bb[0], bb[1]), fmaxf(bb[2], bb[3]));
            atomicMax((int*)&mxs[3 * 64 + (b & 63)], __float_as_int(mb));
        }
    }
}

// ---- fallback GEMM (harness-verified 332us structure, unchanged) ----------
// C = A * B^T, A[M][K], Bm[N][K] row-major fp8 e4m3, fp32 accumulate via
// mfma_scale_f32_16x16x128_f8f6f4 with unit scales (E8M0 0x7F = 2^0).
// LDS XOR-swizzled in 16B chunks: slot (row,c) holds global chunk c^(row&7).
// A-fragment (16x16x128): row=lane&15, k = quad*32 + reg*4 + byte
// -> 32 contiguous bytes = swizzled chunks {(2q)^e, (2q+1)^e}, e=row&7.
// C/D layout: col=lane&15, row=quad*4+reg.
// MODE 1: epilogue sums exp(C[i][j]) into rowsum[i] (scores never hit HBM).
// MODE 2: prologue addv[128]=hardswish(log(rowsum)); epilogue transposed
//         through LDS (stride 132 floats) for coalesced float4 stores of
//         out = clamp(C + bias + addv, -1, 1).
template <int MODE>
__device__ __forceinline__ void gemm_body(
    const uint8_t* __restrict__ A,
    const uint8_t* __restrict__ Bm,
    int K, int N,
    float* __restrict__ rowsum,
    const float* __restrict__ bias,
    float* __restrict__ out) {
    // 33.8 KB: staging (32 KB) during K-loop; 64x132 float pad-buffer after.
    __shared__ __align__(16) uint8_t smem[64 * 132 * 4];
    __shared__ float addv[BM];     // separate: must not alias epi
    uint8_t* As = smem;            // 16 KB
    uint8_t* Bs = smem + 16384;    // 16 KB
    float* epi = (float*)smem;     // MODE 2 epilogue reuse

    const int t = threadIdx.x;
    const int w = t >> 6;
    const int lane = t & 63;
    const int quad = lane >> 4;
    const int lc = lane & 15;
    const int wm = w >> 1;   // wave row (0..1), 64 rows each
    const int wn = w & 1;    // wave col (0..1), 64 cols each
    const int rowBase = blockIdx.y * BM;
    const int colBase = blockIdx.x * BN;

    if constexpr (MODE == 2) {
        // one log per thread; published by the K-loop's first __syncthreads()
        if (t < BM) addv[t] = hardswish_f(logf(rowsum[rowBase + t]));
    }

    floatx4 acc[4][4];
#pragma unroll
    for (int mi = 0; mi < 4; ++mi)
#pragma unroll
        for (int ni = 0; ni < 4; ++ni)
            acc[mi][ni] = (floatx4){0.f, 0.f, 0.f, 0.f};

    const int nIter = K / BK;
    for (int kt = 0; kt < nIter; ++kt) {
        __syncthreads();  // prior iteration's LDS reads complete (+ addv publish)
#pragma unroll
        for (int c = 0; c < 4; ++c) {
            const int idx = c * 256 + t;       // 0..1023 -> 1024 16B chunks each
            const int row = idx >> 3;          // 0..127
            const int cg = (idx & 7) ^ (row & 7);
            gload_lds16(A + (size_t)(rowBase + row) * K + kt * BK + cg * 16, As + idx * 16);
            gload_lds16(Bm + (size_t)(colBase + row) * K + kt * BK + cg * 16, Bs + idx * 16);
        }
        __syncthreads();  // drains vmcnt: staged data visible

        intx8 af[4], bf[4];
#pragma unroll
        for (int mi = 0; mi < 4; ++mi) {
            const int row = wm * 64 + mi * 16 + lc;
            const int e = row & 7;
            ((intx4*)&af[mi])[0] = *(const intx4*)(As + row * BK + ((2 * quad) ^ e) * 16);
            ((intx4*)&af[mi])[1] = *(const intx4*)(As + row * BK + ((2 * quad + 1) ^ e) * 16);
        }
#pragma unroll
        for (int ni = 0; ni < 4; ++ni) {
            const int row = wn * 64 + ni * 16 + lc;
            const int e = row & 7;
            ((intx4*)&bf[ni])[0] = *(const intx4*)(Bs + row * BK + ((2 * quad) ^ e) * 16);
            ((intx4*)&bf[ni])[1] = *(const intx4*)(Bs + row * BK + ((2 * quad + 1) ^ e) * 16);
        }
#pragma unroll
        for (int mi = 0; mi < 4; ++mi)
#pragma unroll
            for (int ni = 0; ni < 4; ++ni)
                acc[mi][ni] = __builtin_amdgcn_mfma_scale_f32_16x16x128_f8f6f4(
                    af[mi], bf[ni], acc[mi][ni],
                    0, 0,                      // cbsz=fp8(e4m3), blgp=fp8(e4m3)
                    0, 0x7F7F7F7F,             // A scale: 1.0
                    0, 0x7F7F7F7F);            // B scale: 1.0
    }

    if constexpr (MODE == 1) {
        // sum exp over this wave's 64 columns for each of its 64 rows
#pragma unroll
        for (int mi = 0; mi < 4; ++mi) {
#pragma unroll
            for (int r = 0; r < 4; ++r) {
                float p = 0.f;
#pragma unroll
                for (int ni = 0; ni < 4; ++ni) p += __expf(acc[mi][ni][r]);
                // butterfly over the 16 columns held by this quad's 16 lanes
                p += __shfl_xor(p, 1, 16);
                p += __shfl_xor(p, 2, 16);
                p += __shfl_xor(p, 4, 16);
                p += __shfl_xor(p, 8, 16);
                if (lc == 0) {
                    int row = rowBase + wm * 64 + mi * 16 + quad * 4 + r;
                    atomicAdd(&rowsum[row], p);
                }
            }
        }
    } else {
        // Two halves (64 rows each): wave-row h dumps its (bias+addv+clamp)ed
        // tile into epi[64][132], then all 256 threads store coalesced float4.
#pragma unroll
        for (int h = 0; h < 2; ++h) {
            __syncthreads();  // epi free (staging reads / prior half done)
            if (wm == h) {
#pragma unroll
                for (int mi = 0; mi < 4; ++mi) {
                    const int lr0 = mi * 16 + quad * 4;    // local row 0..60
#pragma unroll
                    for (int ni = 0; ni < 4; ++ni) {
                        const int c = wn * 64 + ni * 16 + lc;
                        const float bv = bias[colBase + c];
#pragma unroll
                        for (int r = 0; r < 4; ++r) {
                            float v = acc[mi][ni][r] + bv + addv[h * 64 + lr0 + r];
                            v = fminf(fmaxf(v, -1.0f), 1.0f);
                            epi[(lr0 + r) * 132 + c] = v;
                        }
                    }
                }
            }
            __syncthreads();  // epi visible to all
#pragma unroll
            for (int k = 0; k < 8; ++k) {
                const int idx = k * 256 + t;     // 0..2047
                const int row = idx >> 5;        // 0..63
                const int c4 = (idx & 31) * 4;   // 0..124
                float4 v = *(const float4*)&epi[row * 132 + c4];
                *(float4*)&out[(size_t)(rowBase + h * 64 + row) * N + colBase + c4] = v;
            }
        }
    }
}

__global__ __launch_bounds__(256, 3) void k_g1(
    const uint8_t* __restrict__ A, const uint8_t* __restrict__ Bm,
    int K, int N, float* __restrict__ rowsum, const unsigned int* mxs) {
    if (certified(mxs)) return;
    gemm_body<1>(A, Bm, K, N, rowsum, nullptr, nullptr);
}

__global__ __launch_bounds__(256, 3) void k_g2(
    const uint8_t* __restrict__ A, const uint8_t* __restrict__ Bm,
    int K, int N, float* __restrict__ rowsum,
    const float* __restrict__ bias, float* __restrict__ out,
    const unsigned int* mxs) {
    if (certified(mxs)) {
        // Certified saturation: out tile = 1.0f (coalesced float4 stores).
        const int rowBase = blockIdx.y * BM;
        const int colBase = blockIdx.x * BN;
        const int t = threadIdx.x;
        const float4 one = make_float4(1.f, 1.f, 1.f, 1.f);
#pragma unroll
        for (int k = 0; k < 16; ++k) {
            const int idx = k * 256 + t;     // 0..4095
            const int row = idx >> 5;        // 0..127
            const int c4 = (idx & 31) * 4;   // 0..124
            *(float4*)&out[(size_t)(rowBase + row) * N + colBase + c4] = one;
        }
        return;
    }
    gemm_body<2>(A, Bm, K, N, rowsum, bias, out);
}

extern "C" void kernel_launch(void* const* d_in, const int* in_sizes, int n_in,
                              void* d_out, int out_size, void* d_ws, size_t ws_size,
                              hipStream_t stream) {
    const float* x = (const float*)d_in[0];     // [B, F]
    const float* y = (const float*)d_in[1];     // [B, F]
    const float* wt = (const float*)d_in[2];    // [N, F]
    const float* bias = (const float*)d_in[3];  // [N]
    float* out = (float*)d_out;                 // [B, N]

    // Workspace: xq 8MB | yq 8MB | wq 4MB | rowsum 32KB | mxs[4][64] (1KB)
    uint8_t* xq = (uint8_t*)d_ws;
    uint8_t* yq = xq + (size_t)B_DIM * F_DIM;
    uint8_t* wq = yq + (size_t)B_DIM * F_DIM;
    float* rowsum = (float*)(wq + (size_t)N_DIM * F_DIM);
    unsigned int* mxs = (unsigned int*)(rowsum + B_DIM);
    const size_t NEED = (size_t)(2 * B_DIM * F_DIM + N_DIM * F_DIM)
                        + (size_t)B_DIM * 4 + 1024;

    unsigned int* mxp = nullptr;
    if (ws_size >= NEED) {
        // Zero the hashed max slots (capture-safe memset node). Empty slots
        // stay 0 (never lower the max); stale garbage only over-states ->
        // certificate fails -> safe fallback.
        hipMemsetAsync(mxs, 0, 1024, stream);
        mxp = mxs;
    }

    // 1) fused norms + quantize + rowsum-zero (+ hashed atomicMax scalars)
    k_prep<<<1288, 256, 0, stream>>>(x, y, wt, bias, xq, rowsum, mxp);

    // 2) scores = x . y^T, fused exp-rowsum (single merged dispatch;
    //    early-exits when certificate holds)
    k_g1<<<dim3(B_DIM / BN, B_DIM / BM), 256, 0, stream>>>(
        xq, yq, F_DIM, B_DIM, rowsum, mxp);

    // 3) out = y . w^T + bias + hardswish(log(rowsum)), clamped
    //    (or certified fill of 1.0f)
    k_g2<<<dim3(N_DIM / BN, B_DIM / BM), 256, 0, stream>>>(
        yq, wq, F_DIM, N_DIM, rowsum, bias, out, mxp);
}

// Round 25
// 215.278 us; speedup vs baseline: 1.1918x; 1.0062x over previous
//
#include <hip/hip_runtime.h>
#include <cstdint>
#include <cstddef>

// Problem constants (fixed by the reference: B=8192, F=1024, N=4096)
#define B_DIM 8192
#define F_DIM 1024
#define N_DIM 4096

// R20 (resubmit x4 after broker timeouts): cut certified-path WORK (R19
// post-mortem: 216.6 ~= R17's 213.7 -- dispatch count in the 3-6 range is
// ~free; k_prep's quantize+zero work is pure waste when certified, and its
// true cost is unobservable but 20-79us).
//  - k_norms: PURE-READ certification pass (80MB, no stores, hashed
//    atomicMax only) -- roofline ~13us.
//  - k_cvt: quantize + rowsum-zero moved BEHIND the certificate (early-exit
//    ~2us when certified; full ~16us only on the fallback path).
//  - k_g1 / k_g2 / fallback GEMM / certificate: unchanged from R19.
// Scalar Cauchy-Schwarz certificate (margins ~2.3x at reference scales):
//   L := lnB_floor - maxX*maxY >= 3+1/16  (lse_i >= L, hardswish=identity)
//   L - maxY*maxW - maxB >= 1+1/16        (out_pre >= 1 -> clamp = 1)
// certified -> k_cvt/k_g1 exit, k_g2 fills 1.0f (~20us, write-roofline).
// else -> harness-verified fp8 MX pipeline (128x128 tile, 4 waves,
// 3 blocks/CU; R13-R16 local optimum). Hashed slots: empty stay 0 (never
// lower the max); garbage only over-states -> certificate fails -> safe.
#define BM 128
#define BN 128
#define BK 128

typedef float floatx4 __attribute__((ext_vector_type(4)));
typedef int intx4 __attribute__((ext_vector_type(4)));
typedef int intx8 __attribute__((ext_vector_type(8)));

typedef const __attribute__((address_space(1))) unsigned int* as1_u32cp;
typedef __attribute__((address_space(3))) unsigned int* as3_u32p;

// Async global->LDS 16B copy. LDS dest is wave-uniform base + lane*16.
__device__ __forceinline__ void gload_lds16(const uint8_t* g, uint8_t* l) {
    __builtin_amdgcn_global_load_lds((as1_u32cp)(const unsigned int*)g,
                                     (as3_u32p)(unsigned int*)l, 16, 0, 0);
}

__device__ __forceinline__ float hardswish_f(float l) {
    float g = fminf(fmaxf(l + 3.0f, 0.0f), 6.0f);
    return l * g * (1.0f / 6.0f);
}

// Inline certificate: butterfly-max the 64 hashed slots per category.
// All lanes produce the identical value -> wave-uniform branch. lnB_floor =
// 9.0109130 < ln(8192); margin 1/16 covers fp32 summation error (~100x).
__device__ __forceinline__ bool certified(const unsigned int* mxs) {
    if (!mxs) return false;
    const int lane = threadIdx.x & 63;
    float vX = __int_as_float((int)mxs[0 * 64 + lane]);
    float vY = __int_as_float((int)mxs[1 * 64 + lane]);
    float vW = __int_as_float((int)mxs[2 * 64 + lane]);
    float vB = __int_as_float((int)mxs[3 * 64 + lane]);
#pragma unroll
    for (int o = 1; o < 64; o <<= 1) {
        vX = fmaxf(vX, __shfl_xor(vX, o, 64));
        vY = fmaxf(vY, __shfl_xor(vY, o, 64));
        vW = fmaxf(vW, __shfl_xor(vW, o, 64));
        vB = fmaxf(vB, __shfl_xor(vB, o, 64));
    }
    const float L = 9.0109130f - vX * vY;
    return (L >= 3.0625f) && (L - vY * vW - vB >= 1.0625f);
}

// ---- certification pass: row norms only, PURE READ -----------------------
// 1280 blocks x 16 rows (4 rows/wave sequential). Category uniform per
// block (b<512 x, <1024 y, else w). Per row: 4 coalesced float4 loads/lane
// -> sumsq; butterfly; wave keeps max sumsq (one sqrt at the end).
// Block-reduce 4 wave maxima in LDS; ONE hashed atomicMax per block per
// category (+1 for bias on w-blocks): 1536 atomics over 256 slots.
__global__ __launch_bounds__(256) void k_norms(
    const float* __restrict__ x, const float* __restrict__ y,
    const float* __restrict__ wt, const float* __restrict__ bias,
    unsigned int* __restrict__ mxs) {
    const int b = blockIdx.x;                            // 0..1279
    const int t = threadIdx.x;
    const int lane = t & 63;
    const int wv = t >> 6;
    const int cat = (b < 512) ? 0 : (b < 1024 ? 1 : 2);
    const float* base = (cat == 0) ? x : (cat == 1 ? y : wt);
    const int catRow0 = cat * B_DIM;                     // 0 | 8192 | 16384

    float wmaxs = 0.f;   // max sumsq over this wave's 4 rows (all lanes)
    float wmaxb = 0.f;   // max |bias| (lane 0 only, cat 2 only)
#pragma unroll
    for (int r = 0; r < 4; ++r) {
        const int row = b * 16 + wv * 4 + r;             // global 0..20479
        const float* src = base + (size_t)(row - catRow0) * F_DIM;
        float s = 0.f;
#pragma unroll
        for (int j = 0; j < 4; ++j) {
            float4 v = ((const float4*)src)[j * 64 + lane];
            s += v.x * v.x + v.y * v.y + v.z * v.z + v.w * v.w;
        }
#pragma unroll
        for (int o = 1; o < 64; o <<= 1) s += __shfl_xor(s, o, 64);
        wmaxs = fmaxf(wmaxs, s);
        if (cat == 2 && lane == 0)
            wmaxb = fmaxf(wmaxb, fabsf(bias[row - 2 * B_DIM]));
    }

    __shared__ float nrm[4];
    __shared__ float bb[4];
    if (lane == 0) { nrm[wv] = sqrtf(wmaxs); bb[wv] = wmaxb; }
    __syncthreads();
    if (t == 0) {
        float m = fmaxf(fmaxf(nrm[0], nrm[1]), fmaxf(nrm[2], nrm[3]));
        atomicMax((int*)&mxs[cat * 64 + (b & 63)], __float_as_int(m));
        if (cat == 2) {
            float mb = fmaxf(fmaxf(bb[0], bb[1]), fmaxf(bb[2], bb[3]));
            atomicMax((int*)&mxs[3 * 64 + (b & 63)], __float_as_int(mb));
        }
    }
}

// ---- fallback-only: fp8 e4m3 quantize for x|y|w + rowsum-zero tail -------
// Early-exits (~2us) when certificate holds. Grid-stride, 2048 blocks.
__global__ __launch_bounds__(256) void k_cvt(
    const float* __restrict__ x, const float* __restrict__ y,
    const float* __restrict__ wt, uint8_t* __restrict__ dst,
    float* __restrict__ rowsum, int n4x, int n4w, const unsigned int* mxs) {
    if (certified(mxs)) return;
    const int total = 2 * n4x + n4w;
    const int items = total + B_DIM / 4;
    const int stride = gridDim.x * 256;
    for (int i = blockIdx.x * 256 + threadIdx.x; i < items; i += stride) {
        if (i >= total) {
            ((float4*)rowsum)[i - total] = make_float4(0.f, 0.f, 0.f, 0.f);
            continue;
        }
        const float* src;
        int j;
        if (i < n4x) { src = x; j = i; }
        else if (i < 2 * n4x) { src = y; j = i - n4x; }
        else { src = wt; j = i - 2 * n4x; }
        float4 v = ((const float4*)src)[j];
        int p = __builtin_amdgcn_cvt_pk_fp8_f32(v.x, v.y, 0, false);
        p = __builtin_amdgcn_cvt_pk_fp8_f32(v.z, v.w, p, true);
        ((int*)dst)[i] = p;
    }
}

// ---- fallback GEMM (harness-verified 332us structure, unchanged) ----------
// C = A * B^T, A[M][K], Bm[N][K] row-major fp8 e4m3, fp32 accumulate via
// mfma_scale_f32_16x16x128_f8f6f4 with unit scales (E8M0 0x7F = 2^0).
// LDS XOR-swizzled in 16B chunks: slot (row,c) holds global chunk c^(row&7).
// A-fragment (16x16x128): row=lane&15, k = quad*32 + reg*4 + byte
// -> 32 contiguous bytes = swizzled chunks {(2q)^e, (2q+1)^e}, e=row&7.
// C/D layout: col=lane&15, row=quad*4+reg.
// MODE 1: epilogue sums exp(C[i][j]) into rowsum[i] (scores never hit HBM).
// MODE 2: prologue addv[128]=hardswish(log(rowsum)); epilogue transposed
//         through LDS (stride 132 floats) for coalesced float4 stores of
//         out = clamp(C + bias + addv, -1, 1).
template <int MODE>
__device__ __forceinline__ void gemm_body(
    const uint8_t* __restrict__ A,
    const uint8_t* __restrict__ Bm,
    int K, int N,
    float* __restrict__ rowsum,
    const float* __restrict__ bias,
    float* __restrict__ out) {
    // 33.8 KB: staging (32 KB) during K-loop; 64x132 float pad-buffer after.
    __shared__ __align__(16) uint8_t smem[64 * 132 * 4];
    __shared__ float addv[BM];     // separate: must not alias epi
    uint8_t* As = smem;            // 16 KB
    uint8_t* Bs = smem + 16384;    // 16 KB
    float* epi = (float*)smem;     // MODE 2 epilogue reuse

    const int t = threadIdx.x;
    const int w = t >> 6;
    const int lane = t & 63;
    const int quad = lane >> 4;
    const int lc = lane & 15;
    const int wm = w >> 1;   // wave row (0..1), 64 rows each
    const int wn = w & 1;    // wave col (0..1), 64 cols each
    const int rowBase = blockIdx.y * BM;
    const int colBase = blockIdx.x * BN;

    if constexpr (MODE == 2) {
        // one log per thread; published by the K-loop's first __syncthreads()
        if (t < BM) addv[t] = hardswish_f(logf(rowsum[rowBase + t]));
    }

    floatx4 acc[4][4];
#pragma unroll
    for (int mi = 0; mi < 4; ++mi)
#pragma unroll
        for (int ni = 0; ni < 4; ++ni)
            acc[mi][ni] = (floatx4){0.f, 0.f, 0.f, 0.f};

    const int nIter = K / BK;
    for (int kt = 0; kt < nIter; ++kt) {
        __syncthreads();  // prior iteration's LDS reads complete (+ addv publish)
#pragma unroll
        for (int c = 0; c < 4; ++c) {
            const int idx = c * 256 + t;       // 0..1023 -> 1024 16B chunks each
            const int row = idx >> 3;          // 0..127
            const int cg = (idx & 7) ^ (row & 7);
            gload_lds16(A + (size_t)(rowBase + row) * K + kt * BK + cg * 16, As + idx * 16);
            gload_lds16(Bm + (size_t)(colBase + row) * K + kt * BK + cg * 16, Bs + idx * 16);
        }
        __syncthreads();  // drains vmcnt: staged data visible

        intx8 af[4], bf[4];
#pragma unroll
        for (int mi = 0; mi < 4; ++mi) {
            const int row = wm * 64 + mi * 16 + lc;
            const int e = row & 7;
            ((intx4*)&af[mi])[0] = *(const intx4*)(As + row * BK + ((2 * quad) ^ e) * 16);
            ((intx4*)&af[mi])[1] = *(const intx4*)(As + row * BK + ((2 * quad + 1) ^ e) * 16);
        }
#pragma unroll
        for (int ni = 0; ni < 4; ++ni) {
            const int row = wn * 64 + ni * 16 + lc;
            const int e = row & 7;
            ((intx4*)&bf[ni])[0] = *(const intx4*)(Bs + row * BK + ((2 * quad) ^ e) * 16);
            ((intx4*)&bf[ni])[1] = *(const intx4*)(Bs + row * BK + ((2 * quad + 1) ^ e) * 16);
        }
#pragma unroll
        for (int mi = 0; mi < 4; ++mi)
#pragma unroll
            for (int ni = 0; ni < 4; ++ni)
                acc[mi][ni] = __builtin_amdgcn_mfma_scale_f32_16x16x128_f8f6f4(
                    af[mi], bf[ni], acc[mi][ni],
                    0, 0,                      // cbsz=fp8(e4m3), blgp=fp8(e4m3)
                    0, 0x7F7F7F7F,             // A scale: 1.0
                    0, 0x7F7F7F7F);            // B scale: 1.0
    }

    if constexpr (MODE == 1) {
        // sum exp over this wave's 64 columns for each of its 64 rows
#pragma unroll
        for (int mi = 0; mi < 4; ++mi) {
#pragma unroll
            for (int r = 0; r < 4; ++r) {
                float p = 0.f;
#pragma unroll
                for (int ni = 0; ni < 4; ++ni) p += __expf(acc[mi][ni][r]);
                // butterfly over the 16 columns held by this quad's 16 lanes
                p += __shfl_xor(p, 1, 16);
                p += __shfl_xor(p, 2, 16);
                p += __shfl_xor(p, 4, 16);
                p += __shfl_xor(p, 8, 16);
                if (lc == 0) {
                    int row = rowBase + wm * 64 + mi * 16 + quad * 4 + r;
                    atomicAdd(&rowsum[row], p);
                }
            }
        }
    } else {
        // Two halves (64 rows each): wave-row h dumps its (bias+addv+clamp)ed
        // tile into epi[64][132], then all 256 threads store coalesced float4.
#pragma unroll
        for (int h = 0; h < 2; ++h) {
            __syncthreads();  // epi free (staging reads / prior half done)
            if (wm == h) {
#pragma unroll
                for (int mi = 0; mi < 4; ++mi) {
                    const int lr0 = mi * 16 + quad * 4;    // local row 0..60
#pragma unroll
                    for (int ni = 0; ni < 4; ++ni) {
                        const int c = wn * 64 + ni * 16 + lc;
                        const float bv = bias[colBase + c];
#pragma unroll
                        for (int r = 0; r < 4; ++r) {
                            float v = acc[mi][ni][r] + bv + addv[h * 64 + lr0 + r];
                            v = fminf(fmaxf(v, -1.0f), 1.0f);
                            epi[(lr0 + r) * 132 + c] = v;
                        }
                    }
                }
            }
            __syncthreads();  // epi visible to all
#pragma unroll
            for (int k = 0; k < 8; ++k) {
                const int idx = k * 256 + t;     // 0..2047
                const int row = idx >> 5;        // 0..63
                const int c4 = (idx & 31) * 4;   // 0..124
                float4 v = *(const float4*)&epi[row * 132 + c4];
                *(float4*)&out[(size_t)(rowBase + h * 64 + row) * N + colBase + c4] = v;
            }
        }
    }
}

__global__ __launch_bounds__(256, 3) void k_g1(
    const uint8_t* __restrict__ A, const uint8_t* __restrict__ Bm,
    int K, int N, float* __restrict__ rowsum, const unsigned int* mxs) {
    if (certified(mxs)) return;
    gemm_body<1>(A, Bm, K, N, rowsum, nullptr, nullptr);
}

__global__ __launch_bounds__(256, 3) void k_g2(
    const uint8_t* __restrict__ A, const uint8_t* __restrict__ Bm,
    int K, int N, float* __restrict__ rowsum,
    const float* __restrict__ bias, float* __restrict__ out,
    const unsigned int* mxs) {
    if (certified(mxs)) {
        // Certified saturation: out tile = 1.0f (coalesced float4 stores).
        const int rowBase = blockIdx.y * BM;
        const int colBase = blockIdx.x * BN;
        const int t = threadIdx.x;
        const float4 one = make_float4(1.f, 1.f, 1.f, 1.f);
#pragma unroll
        for (int k = 0; k < 16; ++k) {
            const int idx = k * 256 + t;     // 0..4095
            const int row = idx >> 5;        // 0..127
            const int c4 = (idx & 31) * 4;   // 0..124
            *(float4*)&out[(size_t)(rowBase + row) * N + colBase + c4] = one;
        }
        return;
    }
    gemm_body<2>(A, Bm, K, N, rowsum, bias, out);
}

extern "C" void kernel_launch(void* const* d_in, const int* in_sizes, int n_in,
                              void* d_out, int out_size, void* d_ws, size_t ws_size,
                              hipStream_t stream) {
    const float* x = (const float*)d_in[0];     // [B, F]
    const float* y = (const float*)d_in[1];     // [B, F]
    const float* wt = (const float*)d_in[2];    // [N, F]
    const float* bias = (const float*)d_in[3];  // [N]
    float* out = (float*)d_out;                 // [B, N]

    // Workspace: xq 8MB | yq 8MB | wq 4MB | rowsum 32KB | mxs[4][64] (1KB)
    uint8_t* xq = (uint8_t*)d_ws;
    uint8_t* yq = xq + (size_t)B_DIM * F_DIM;
    uint8_t* wq = yq + (size_t)B_DIM * F_DIM;
    float* rowsum = (float*)(wq + (size_t)N_DIM * F_DIM);
    unsigned int* mxs = (unsigned int*)(rowsum + B_DIM);
    const size_t NEED = (size_t)(2 * B_DIM * F_DIM + N_DIM * F_DIM)
                        + (size_t)B_DIM * 4 + 1024;

    unsigned int* mxp = nullptr;
    if (ws_size >= NEED) {
        // Zero the hashed max slots (capture-safe memset node), then the
        // pure-read certification pass. Empty slots stay 0; stale garbage
        // only over-states -> certificate fails -> safe fallback.
        hipMemsetAsync(mxs, 0, 1024, stream);
        k_norms<<<1280, 256, 0, stream>>>(x, y, wt, bias, mxs);
        mxp = mxs;
    }

    const int n4_x = B_DIM * F_DIM / 4;
    const int n4_w = N_DIM * F_DIM / 4;

    // Fallback-only quantize + rowsum-zero (early-exits when certified).
    k_cvt<<<2048, 256, 0, stream>>>(x, y, wt, xq, rowsum, n4_x, n4_w, mxp);

    // scores = x . y^T, fused exp-rowsum (early-exits when certified)
    k_g1<<<dim3(B_DIM / BN, B_DIM / BM), 256, 0, stream>>>(
        xq, yq, F_DIM, B_DIM, rowsum, mxp);

    // out = y . w^T + bias + hardswish(log(rowsum)), clamped
    // (or certified fill of 1.0f)
    k_g2<<<dim3(N_DIM / BN, B_DIM / BM), 256, 0, stream>>>(
        yq, wq, F_DIM, N_DIM, rowsum, bias, out, mxp);
}